// Round 1
// baseline (2519.658 us; speedup 1.0000x reference)
//
#include <hip/hip_runtime.h>

// ODELayer RK4 scan — R5 "swapped-operand B-frag dataflow":
//   Phase 1 (scan_kernel, 64 WG x 512 thr): every GEMM computed as
//   D = W (reg-resident A-frags) x h^T (LDS B-frags). Batch index stays in
//   lane&15 on producer and consumer sides, so stage outputs are written
//   straight into B-fragment layout (2x v_cvt_pk_bf16_f32 + 1 ds_write_b64
//   per 16x16 tile) — no scalar b16 writes, no f2b chains.
//   Asymmetric crews halve read replication: waves 0-3 own W2 and run S2;
//   waves 4-7 own Wlin+W3 and run S3 + RK4 state. S1 on all 8 waves.
//   LDS instrs/eval: 96 ds_read_b128 + ~40 ds_write_b64 (was 168 + ~160 b16).
//   Weight arrays aliased into one wx[32] so divergent crews share registers.
//   Phase 2 (outnet_kernel): unchanged from R4 (xall layout identical).
// All global data f32; MFMA math bf16, f32 accumulate (numerics unchanged).

#define TSTEPS 256
#define BATCH  1024
#define NUQ    32
#define NXQ    128
#define NFQ    256
#define NINQ   160
#define NY     ((size_t)TSTEPS * BATCH * NXQ)

typedef __attribute__((ext_vector_type(8))) short bf16x8;
typedef __attribute__((ext_vector_type(4))) short s16x4;
typedef __attribute__((ext_vector_type(4))) float f32x4;
typedef unsigned short u16;

__device__ __forceinline__ u16 f2b(float f) {
  unsigned u = __float_as_uint(f);
  u = (u + 0x7FFFu + ((u >> 16) & 1u)) >> 16;
  return (u16)u;
}
__device__ __forceinline__ unsigned cvtpk(float a, float b) {
  unsigned r;
  asm("v_cvt_pk_bf16_f32 %0, %1, %2" : "=v"(r) : "v"(a), "v"(b));
  return r;
}
__device__ __forceinline__ f32x4 mfma16(bf16x8 a, bf16x8 b, f32x4 c) {
  return __builtin_amdgcn_mfma_f32_16x16x32_bf16(a, b, c, 0, 0, 0);
}
// 8 consecutive f32 weights -> bf16 fragment (16B-aligned source).
__device__ __forceinline__ bf16x8 ldw8f(const float* p) {
  f32x4 a = *reinterpret_cast<const f32x4*>(p);
  f32x4 b = *reinterpret_cast<const f32x4*>(p + 4);
  bf16x8 r;
  r[0] = (short)f2b(a[0]); r[1] = (short)f2b(a[1]);
  r[2] = (short)f2b(a[2]); r[3] = (short)f2b(a[3]);
  r[4] = (short)f2b(b[0]); r[5] = (short)f2b(b[1]);
  r[6] = (short)f2b(b[2]); r[7] = (short)f2b(b[3]);
  return r;
}

// LDS map: B-frag buffers, frag = [64 lanes][16B], frag kt at +1024*kt.
#define ZOFF  0       // z^T x-part: 4 frags (4 KiB)
#define H1OFF 4096    // h1^T: 8 frags (8 KiB)
#define H2OFF 12288   // h2^T: 8 frags (8 KiB)
#define SMEMB 20480

// ======================= Phase 1: the sequential scan =======================
__global__ __launch_bounds__(512, 2)
void scan_kernel(const float* __restrict__ uin,   // [256][1024][32]
                 const float* __restrict__ x0,    // [1024][128]
                 const float* __restrict__ dtp,
                 const float* __restrict__ Wlin,  // [128][160]
                 const float* __restrict__ W1,    // [256][160]
                 const float* __restrict__ b1,    // [256]
                 const float* __restrict__ W2,    // [256][256]
                 const float* __restrict__ b2,    // [256]
                 const float* __restrict__ W3,    // [128][256]
                 const float* __restrict__ b3,    // [128]
                 u16* __restrict__ xall,          // [256][1024][128] bf16
                 float* __restrict__ out)         // xf at out[NY..]
{
  __shared__ __align__(16) char smem[SMEMB];

  const int tid  = threadIdx.x;
  const int wg   = blockIdx.x;            // batch rows wg*16..+15
  const int lane = tid & 63;
  const int v    = tid >> 6;              // wave 0..7
  const int ln   = lane & 15;             // batch index within row-group
  const int q    = lane >> 4;
  const int w    = v - 4;                 // crew-B index (valid when v>=4)
  const bool crewB = (v >= 4);

  const float dt  = dtp[0];
  const float dth = 0.5f * dt;
  const float dt6 = dt * (1.0f / 6.0f);
  const f32x4 zero4 = {0.f, 0.f, 0.f, 0.f};

  // Producer-side write offset within a frag pair:
  // value (feat 16t+4q+r, batch ln) -> byte 512*t + wby (+2r inside the b64)
  const int wby = 256 * (q >> 1) + 16 * ln + 8 * (q & 1);

  // ---------------- register-resident A-fragments (weights) ----------------
  // A-frag for n-tile T, K-tile kt: lane holds W[16T+ln][32kt+8q+j], j=0..7.
  bf16x8 wc[5][2];   // W1, h1 tiles {2v, 2v+1} (all waves)
  bf16x8 wx[32];     // crewA: W2 frags wx[4*kt+i], tiles 4v+i  (i=0..3)
                     // crewB: Wlin wx[2*kt+i] (tiles 2w+i), W3 wx[10+2*kt+i]
#pragma unroll
  for (int kt = 0; kt < 5; kt++)
#pragma unroll
    for (int i = 0; i < 2; i++)
      wc[kt][i] = ldw8f(W1 + (size_t)(16 * (2 * v + i) + ln) * NINQ + 32 * kt + 8 * q);
  if (!crewB) {
#pragma unroll
    for (int kt = 0; kt < 8; kt++)
#pragma unroll
      for (int i = 0; i < 4; i++)
        wx[4 * kt + i] = ldw8f(W2 + (size_t)(16 * (4 * v + i) + ln) * NFQ + 32 * kt + 8 * q);
  } else {
#pragma unroll
    for (int kt = 0; kt < 5; kt++)
#pragma unroll
      for (int i = 0; i < 2; i++)
        wx[2 * kt + i] = ldw8f(Wlin + (size_t)(16 * (2 * w + i) + ln) * NINQ + 32 * kt + 8 * q);
#pragma unroll
    for (int kt = 0; kt < 8; kt++)
#pragma unroll
      for (int i = 0; i < 2; i++)
        wx[10 + 2 * kt + i] = ldw8f(W3 + (size_t)(16 * (2 * w + i) + ln) * NFQ + 32 * kt + 8 * q);
  }

  // RK4 state on crewB: xs[i][r] = x[batch ln][xdim 16*(2w+i)+4q+r]
  f32x4 xs[2], ksum[2], accl[2];
  if (crewB) {
#pragma unroll
    for (int i = 0; i < 2; i++) {
      xs[i] = *reinterpret_cast<const f32x4*>(
          x0 + (size_t)(wg * 16 + ln) * NXQ + 16 * (2 * w + i) + 4 * q);
      uint2 p;
      p.x = cvtpk(xs[i][0], xs[i][1]);
      p.y = cvtpk(xs[i][2], xs[i][3]);
      *reinterpret_cast<uint2*>(smem + ZOFF + 512 * (2 * w + i) + wby) = p;
    }
  }
  // u B-frag (register-resident, all waves): lane holds u[ln][8q+j]
  bf16x8 uf = ldw8f(uin + (size_t)(wg * 16 + ln) * NUQ + 8 * q);
  __syncthreads();

#pragma unroll 1
  for (int t = 0; t < TSTEPS; t++) {
#pragma unroll 1
    for (int e = 0; e < 4; e++) {
      // ---- S1: h1^T = W1 z^T (all waves, 2 tiles) + lin (crewB) ----
      {
        bf16x8 zf[4];
#pragma unroll
        for (int kt = 0; kt < 4; kt++)
          zf[kt] = *reinterpret_cast<const bf16x8*>(smem + ZOFF + 1024 * kt + 16 * lane);
        f32x4 a0 = zero4, a1 = zero4;
#pragma unroll
        for (int kt = 0; kt < 4; kt++) {
          a0 = mfma16(wc[kt][0], zf[kt], a0);
          a1 = mfma16(wc[kt][1], zf[kt], a1);
        }
        a0 = mfma16(wc[4][0], uf, a0);
        a1 = mfma16(wc[4][1], uf, a1);
        if (crewB) {
          accl[0] = zero4; accl[1] = zero4;
#pragma unroll
          for (int kt = 0; kt < 4; kt++) {
            accl[0] = mfma16(wx[2 * kt + 0], zf[kt], accl[0]);
            accl[1] = mfma16(wx[2 * kt + 1], zf[kt], accl[1]);
          }
          accl[0] = mfma16(wx[8], uf, accl[0]);
          accl[1] = mfma16(wx[9], uf, accl[1]);
        }
#pragma unroll
        for (int i = 0; i < 2; i++) {
          f32x4 d = i ? a1 : a0;
          f32x4 bb = *reinterpret_cast<const f32x4*>(b1 + 16 * (2 * v + i) + 4 * q);
          uint2 p;
          p.x = cvtpk(fmaxf(d[0] + bb[0], 0.f), fmaxf(d[1] + bb[1], 0.f));
          p.y = cvtpk(fmaxf(d[2] + bb[2], 0.f), fmaxf(d[3] + bb[3], 0.f));
          *reinterpret_cast<uint2*>(smem + H1OFF + 512 * (2 * v + i) + wby) = p;
        }
      }
      __syncthreads();
      // ---- S2: h2^T = W2 h1^T (crewA only, 4 tiles) ----
      if (!crewB) {
        f32x4 d[4] = {zero4, zero4, zero4, zero4};
#pragma unroll
        for (int kt = 0; kt < 8; kt++) {
          bf16x8 g = *reinterpret_cast<const bf16x8*>(smem + H1OFF + 1024 * kt + 16 * lane);
          d[0] = mfma16(wx[4 * kt + 0], g, d[0]);
          d[1] = mfma16(wx[4 * kt + 1], g, d[1]);
          d[2] = mfma16(wx[4 * kt + 2], g, d[2]);
          d[3] = mfma16(wx[4 * kt + 3], g, d[3]);
        }
#pragma unroll
        for (int i = 0; i < 4; i++) {
          f32x4 bb = *reinterpret_cast<const f32x4*>(b2 + 16 * (4 * v + i) + 4 * q);
          uint2 p;
          p.x = cvtpk(fmaxf(d[i][0] + bb[0], 0.f), fmaxf(d[i][1] + bb[1], 0.f));
          p.y = cvtpk(fmaxf(d[i][2] + bb[2], 0.f), fmaxf(d[i][3] + bb[3], 0.f));
          *reinterpret_cast<uint2*>(smem + H2OFF + 512 * (4 * v + i) + wby) = p;
        }
      }
      __syncthreads();
      // u prefetch for next step (all waves; S1 of e==3 already consumed uf)
      if (e == 3 && t + 1 < TSTEPS)
        uf = ldw8f(uin + ((size_t)(t + 1) * BATCH + wg * 16 + ln) * NUQ + 8 * q);
      // ---- S3: k = W3 h2^T + lin + b3 ; RK4 update (crewB only) ----
      if (crewB) {
        f32x4 k0 = zero4, k1 = zero4;
#pragma unroll
        for (int kt = 0; kt < 8; kt++) {
          bf16x8 g = *reinterpret_cast<const bf16x8*>(smem + H2OFF + 1024 * kt + 16 * lane);
          k0 = mfma16(wx[10 + 2 * kt + 0], g, k0);
          k1 = mfma16(wx[10 + 2 * kt + 1], g, k1);
        }
        const float wk = (e == 1 || e == 2) ? 2.0f : 1.0f;
        const float cn = (e == 2) ? dt : dth;
        f32x4 kk[2] = {k0, k1};
#pragma unroll
        for (int i = 0; i < 2; i++) {
          f32x4 bb = *reinterpret_cast<const f32x4*>(b3 + 16 * (2 * w + i) + 4 * q);
          float xe[4];
#pragma unroll
          for (int r = 0; r < 4; r++) {
            float kv = kk[i][r] + accl[i][r] + bb[r];
            if (e == 0) ksum[i][r] = kv; else ksum[i][r] += wk * kv;
            if (e == 3) { xs[i][r] += dt6 * ksum[i][r]; xe[r] = xs[i][r]; }
            else        { xe[r] = xs[i][r] + cn * kv; }
          }
          uint2 p;
          p.x = cvtpk(xe[0], xe[1]);
          p.y = cvtpk(xe[2], xe[3]);
          *reinterpret_cast<uint2*>(smem + ZOFF + 512 * (2 * w + i) + wby) = p;
          if (e == 3)
            *reinterpret_cast<uint2*>(
                xall + ((size_t)t * BATCH + wg * 16 + ln) * NXQ + 16 * (2 * w + i) + 4 * q) = p;
        }
      }
      __syncthreads();
    }
  }

  // x_final (f32), vectorized
  if (crewB) {
#pragma unroll
    for (int i = 0; i < 2; i++)
      *reinterpret_cast<f32x4*>(
          out + NY + (size_t)(wg * 16 + ln) * NXQ + 16 * (2 * w + i) + 4 * q) = xs[i];
  }
}

// ======================= Phase 2: bulk out_net GEMM =========================
// Processes y rows [16*slab .. ) for slabs in [slab0+blk*spw, slab_end).
__global__ __launch_bounds__(512, 2)
void outnet_kernel(const u16* __restrict__ xall,  // [rows][128] bf16
                   const float* __restrict__ Wo1, const float* __restrict__ bo1,
                   const float* __restrict__ Wo2, const float* __restrict__ bo2,
                   const float* __restrict__ Wo3, const float* __restrict__ bo3,
                   float* __restrict__ out,       // y [rows][128] f32
                   int slab0, int slab_end, int spw)
{
  __shared__ u16 h1[2][16][264];
  __shared__ u16 h2[2][16][264];

  const int tid  = threadIdx.x;
  const int lane = tid & 63;
  const int v    = tid >> 6;
  const int ln   = lane & 15;
  const int q    = lane >> 4;
  const int n1   = 16 * v + ln;
  const int n2   = 128 + n1;
  const f32x4 zero4 = {0.f, 0.f, 0.f, 0.f};

  bf16x8 f1[4][2];
#pragma unroll
  for (int kt = 0; kt < 4; kt++) {
    int k = 32 * kt + 8 * q;
    f1[kt][0] = ldw8f(Wo1 + n1 * NXQ + k);
    f1[kt][1] = ldw8f(Wo1 + n2 * NXQ + k);
  }
  bf16x8 f2[8][2];
#pragma unroll
  for (int kt = 0; kt < 8; kt++) {
    int k = 32 * kt + 8 * q;
    f2[kt][0] = ldw8f(Wo2 + n1 * NFQ + k);
    f2[kt][1] = ldw8f(Wo2 + n2 * NFQ + k);
  }
  bf16x8 f3[8];
#pragma unroll
  for (int kt = 0; kt < 8; kt++)
    f3[kt] = ldw8f(Wo3 + n1 * NFQ + 32 * kt + 8 * q);

  const float c1a = bo1[n1], c1b = bo1[n2];
  const float c2a = bo2[n1], c2b = bo2[n2];
  const float c3  = bo3[n1];

  const int s0  = slab0 + (int)blockIdx.x * spw;
  int cnt = slab_end - s0; if (cnt > spw) cnt = spw;
  if (cnt <= 0) return;

  bf16x8 a[4], an[4];
#pragma unroll
  for (int kt = 0; kt < 4; kt++)
    a[kt] = *reinterpret_cast<const bf16x8*>(
        &xall[((size_t)16 * s0 + ln) * NXQ + 32 * kt + 8 * q]);

#pragma unroll 1
  for (int i = 0; i < cnt; i++) {
    const int s = s0 + i, par = i & 1;
    if (i + 1 < cnt) {
#pragma unroll
      for (int kt = 0; kt < 4; kt++)
        an[kt] = *reinterpret_cast<const bf16x8*>(
            &xall[((size_t)16 * (s + 1) + ln) * NXQ + 32 * kt + 8 * q]);
    }
    // o1
    {
      f32x4 d0 = zero4, d1 = zero4;
#pragma unroll
      for (int kt = 0; kt < 4; kt++) {
        d0 = mfma16(a[kt], f1[kt][0], d0);
        d1 = mfma16(a[kt], f1[kt][1], d1);
      }
#pragma unroll
      for (int r = 0; r < 4; r++) {
        h1[par][4 * q + r][n1] = f2b(fmaxf(d0[r] + c1a, 0.f));
        h1[par][4 * q + r][n2] = f2b(fmaxf(d1[r] + c1b, 0.f));
      }
    }
    __syncthreads();
    // o2
    {
      bf16x8 c[8];
#pragma unroll
      for (int kt = 0; kt < 8; kt++)
        c[kt] = *reinterpret_cast<const bf16x8*>(&h1[par][ln][32 * kt + 8 * q]);
      f32x4 e0 = zero4, e1 = zero4;
#pragma unroll
      for (int kt = 0; kt < 8; kt++) {
        e0 = mfma16(c[kt], f2[kt][0], e0);
        e1 = mfma16(c[kt], f2[kt][1], e1);
      }
#pragma unroll
      for (int r = 0; r < 4; r++) {
        h2[par][4 * q + r][n1] = f2b(fmaxf(e0[r] + c2a, 0.f));
        h2[par][4 * q + r][n2] = f2b(fmaxf(e1[r] + c2b, 0.f));
      }
    }
    __syncthreads();
    // o3 -> y (f32); no trailing barrier (ping-pong buffers)
    {
      bf16x8 g[8];
#pragma unroll
      for (int kt = 0; kt < 8; kt++)
        g[kt] = *reinterpret_cast<const bf16x8*>(&h2[par][ln][32 * kt + 8 * q]);
      f32x4 y = zero4;
#pragma unroll
      for (int kt = 0; kt < 8; kt++) y = mfma16(g[kt], f3[kt], y);
#pragma unroll
      for (int r = 0; r < 4; r++)
        out[((size_t)16 * s + 4 * q + r) * NXQ + n1] = y[r] + c3;
    }
#pragma unroll
    for (int kt = 0; kt < 4; kt++) a[kt] = an[kt];
  }
}

extern "C" void kernel_launch(void* const* d_in, const int* in_sizes, int n_in,
                              void* d_out, int out_size, void* d_ws, size_t ws_size,
                              hipStream_t stream) {
  const float* uin  = (const float*)d_in[0];
  const float* x0   = (const float*)d_in[1];
  const float* dtp  = (const float*)d_in[2];
  const float* Wlin = (const float*)d_in[3];
  const float* W1   = (const float*)d_in[4];
  const float* b1   = (const float*)d_in[5];
  const float* W2   = (const float*)d_in[6];
  const float* b2   = (const float*)d_in[7];
  const float* W3   = (const float*)d_in[8];
  const float* b3   = (const float*)d_in[9];
  const float* Wo1  = (const float*)d_in[10];
  const float* bo1  = (const float*)d_in[11];
  const float* Wo2  = (const float*)d_in[12];
  const float* bo2  = (const float*)d_in[13];
  const float* Wo3  = (const float*)d_in[14];
  const float* bo3  = (const float*)d_in[15];
  float* out = (float*)d_out;

  const size_t xall_bytes = NY * sizeof(u16);   // 64 MiB
  const bool ws_ok = (ws_size >= xall_bytes);
  u16* xall = ws_ok ? (u16*)d_ws : (u16*)d_out;  // fallback: front of y region

  scan_kernel<<<dim3(64), dim3(512), 0, stream>>>(
      uin, x0, dtp, Wlin, W1, b1, W2, b2, W3, b3, xall, out);

  const int nslab = TSTEPS * BATCH / 16;        // 16384
  if (ws_ok) {
    const int spw = 32;
    outnet_kernel<<<dim3(nslab / spw), dim3(512), 0, stream>>>(
        xall, Wo1, bo1, Wo2, bo2, Wo3, bo3, out, 0, nslab, spw);
  } else {
    // y[slab s] overwrites x-slabs [2s,2s+2): process [S,2S) in halving
    // passes so clobbered x-slabs are always already consumed.
    for (int S = nslab / 2; S >= 1; S >>= 1) {
      int grid = S < 512 ? S : 512;
      int spw  = (S + grid - 1) / grid;
      outnet_kernel<<<dim3(grid), dim3(512), 0, stream>>>(
          xall, Wo1, bo1, Wo2, bo2, Wo3, bo3, out, S, 2 * S, spw);
    }
    outnet_kernel<<<dim3(1), dim3(512), 0, stream>>>(
        xall, Wo1, bo1, Wo2, bo2, Wo3, bo3, out, 0, 1, 1);
  }
}

// Round 2
// 2096.999 us; speedup vs baseline: 1.2016x; 1.2016x over previous
//
#include <hip/hip_runtime.h>

// ODELayer RK4 scan — R6: R5's swapped-operand B-frag dataflow with the
// latency bugs fixed:
//   * biases hoisted to registers BEFORE the t-loop (R5 reloaded them from
//     global every stage; __syncthreads blocks LICM -> vmcnt stall/stage).
//   * S2/S3 LDS reads batched into g[4] arrays ahead of the MFMA groups
//     (R5 fused read+mfma per kt -> ~8 serialized LDS latencies per stage).
//   * u[t+1] issued as raw f32x4 loads at e==0, converted at e==3 (HBM
//     latency hidden under ~10 stages instead of ~2).
// Structure otherwise identical to R5: crewA (waves 0-3) owns W2/S2,
// crewB (waves 4-7) owns Wlin+W3+RK4 state/S3; S1 on all 8 waves.
// Phase 2 (outnet_kernel) unchanged.

#define TSTEPS 256
#define BATCH  1024
#define NUQ    32
#define NXQ    128
#define NFQ    256
#define NINQ   160
#define NY     ((size_t)TSTEPS * BATCH * NXQ)

typedef __attribute__((ext_vector_type(8))) short bf16x8;
typedef __attribute__((ext_vector_type(4))) short s16x4;
typedef __attribute__((ext_vector_type(4))) float f32x4;
typedef unsigned short u16;

__device__ __forceinline__ u16 f2b(float f) {
  unsigned u = __float_as_uint(f);
  u = (u + 0x7FFFu + ((u >> 16) & 1u)) >> 16;
  return (u16)u;
}
__device__ __forceinline__ unsigned cvtpk(float a, float b) {
  unsigned r;
  asm("v_cvt_pk_bf16_f32 %0, %1, %2" : "=v"(r) : "v"(a), "v"(b));
  return r;
}
__device__ __forceinline__ f32x4 mfma16(bf16x8 a, bf16x8 b, f32x4 c) {
  return __builtin_amdgcn_mfma_f32_16x16x32_bf16(a, b, c, 0, 0, 0);
}
// 8 consecutive f32 weights -> bf16 fragment (16B-aligned source).
__device__ __forceinline__ bf16x8 ldw8f(const float* p) {
  f32x4 a = *reinterpret_cast<const f32x4*>(p);
  f32x4 b = *reinterpret_cast<const f32x4*>(p + 4);
  bf16x8 r;
  r[0] = (short)f2b(a[0]); r[1] = (short)f2b(a[1]);
  r[2] = (short)f2b(a[2]); r[3] = (short)f2b(a[3]);
  r[4] = (short)f2b(b[0]); r[5] = (short)f2b(b[1]);
  r[6] = (short)f2b(b[2]); r[7] = (short)f2b(b[3]);
  return r;
}

// LDS map: B-frag buffers, frag = [64 lanes][16B], frag kt at +1024*kt.
#define ZOFF  0       // z^T x-part: 4 frags (4 KiB)
#define H1OFF 4096    // h1^T: 8 frags (8 KiB)
#define H2OFF 12288   // h2^T: 8 frags (8 KiB)
#define SMEMB 20480

// ======================= Phase 1: the sequential scan =======================
__global__ __launch_bounds__(512, 2)
void scan_kernel(const float* __restrict__ uin,   // [256][1024][32]
                 const float* __restrict__ x0,    // [1024][128]
                 const float* __restrict__ dtp,
                 const float* __restrict__ Wlin,  // [128][160]
                 const float* __restrict__ W1,    // [256][160]
                 const float* __restrict__ b1,    // [256]
                 const float* __restrict__ W2,    // [256][256]
                 const float* __restrict__ b2,    // [256]
                 const float* __restrict__ W3,    // [128][256]
                 const float* __restrict__ b3,    // [128]
                 u16* __restrict__ xall,          // [256][1024][128] bf16
                 float* __restrict__ out)         // xf at out[NY..]
{
  __shared__ __align__(16) char smem[SMEMB];

  const int tid  = threadIdx.x;
  const int wg   = blockIdx.x;            // batch rows wg*16..+15
  const int lane = tid & 63;
  const int v    = tid >> 6;              // wave 0..7
  const int ln   = lane & 15;             // batch index within row-group
  const int q    = lane >> 4;
  const int w    = v - 4;                 // crew-B index (valid when v>=4)
  const bool crewB = (v >= 4);

  const float dt  = dtp[0];
  const float dth = 0.5f * dt;
  const float dt6 = dt * (1.0f / 6.0f);
  const f32x4 zero4 = {0.f, 0.f, 0.f, 0.f};

  // Producer-side write offset within a frag pair:
  // value (feat 16T+4q+r, batch ln) -> byte 512*T + wby (+2r inside the b64)
  const int wby = 256 * (q >> 1) + 16 * ln + 8 * (q & 1);

  // ---------------- register-resident A-fragments (weights) ----------------
  // A-frag for n-tile T, K-tile kt: lane holds W[16T+ln][32kt+8q+j], j=0..7.
  bf16x8 wc[5][2];   // W1, h1 tiles {2v, 2v+1} (all waves)
  bf16x8 wx[32];     // crewA: W2 frags wx[4*kt+i], tiles 4v+i  (i=0..3)
                     // crewB: Wlin wx[2*kt+i] (tiles 2w+i), W3 wx[10+2*kt+i]
#pragma unroll
  for (int kt = 0; kt < 5; kt++)
#pragma unroll
    for (int i = 0; i < 2; i++)
      wc[kt][i] = ldw8f(W1 + (size_t)(16 * (2 * v + i) + ln) * NINQ + 32 * kt + 8 * q);
  if (!crewB) {
#pragma unroll
    for (int kt = 0; kt < 8; kt++)
#pragma unroll
      for (int i = 0; i < 4; i++)
        wx[4 * kt + i] = ldw8f(W2 + (size_t)(16 * (4 * v + i) + ln) * NFQ + 32 * kt + 8 * q);
  } else {
#pragma unroll
    for (int kt = 0; kt < 5; kt++)
#pragma unroll
      for (int i = 0; i < 2; i++)
        wx[2 * kt + i] = ldw8f(Wlin + (size_t)(16 * (2 * w + i) + ln) * NINQ + 32 * kt + 8 * q);
#pragma unroll
    for (int kt = 0; kt < 8; kt++)
#pragma unroll
      for (int i = 0; i < 2; i++)
        wx[10 + 2 * kt + i] = ldw8f(W3 + (size_t)(16 * (2 * w + i) + ln) * NFQ + 32 * kt + 8 * q);
  }

  // ---- biases in registers (NOT reloaded in-loop: barriers block LICM) ----
  f32x4 bb1[2];                         // b1 for h1-tiles {2v, 2v+1}
#pragma unroll
  for (int i = 0; i < 2; i++)
    bb1[i] = *reinterpret_cast<const f32x4*>(b1 + 16 * (2 * v + i) + 4 * q);
  f32x4 bbx[4] = {zero4, zero4, zero4, zero4};
  if (!crewB) {                          // crewA: b2 for h2-tiles {4v+i}
#pragma unroll
    for (int i = 0; i < 4; i++)
      bbx[i] = *reinterpret_cast<const f32x4*>(b2 + 16 * (4 * v + i) + 4 * q);
  } else {                               // crewB: b3 for k-tiles {2w+i}
#pragma unroll
    for (int i = 0; i < 2; i++)
      bbx[i] = *reinterpret_cast<const f32x4*>(b3 + 16 * (2 * w + i) + 4 * q);
  }

  // RK4 state on crewB: xs[i][r] = x[batch ln][xdim 16*(2w+i)+4q+r]
  f32x4 xs[2], ksum[2], accl[2];
  if (crewB) {
#pragma unroll
    for (int i = 0; i < 2; i++) {
      xs[i] = *reinterpret_cast<const f32x4*>(
          x0 + (size_t)(wg * 16 + ln) * NXQ + 16 * (2 * w + i) + 4 * q);
      uint2 p;
      p.x = cvtpk(xs[i][0], xs[i][1]);
      p.y = cvtpk(xs[i][2], xs[i][3]);
      *reinterpret_cast<uint2*>(smem + ZOFF + 512 * (2 * w + i) + wby) = p;
    }
  }
  // u B-frag (register-resident, all waves): lane holds u[ln][8q+j]
  bf16x8 uf = ldw8f(uin + (size_t)(wg * 16 + ln) * NUQ + 8 * q);
  f32x4 ur0 = zero4, ur1 = zero4;        // raw u[t+1], issued at e==0
  __syncthreads();

#pragma unroll 1
  for (int t = 0; t < TSTEPS; t++) {
#pragma unroll 1
    for (int e = 0; e < 4; e++) {
      // ---- S1: h1^T = W1 z^T (all waves, 2 tiles) + lin (crewB) ----
      {
        bf16x8 zf[4];
#pragma unroll
        for (int kt = 0; kt < 4; kt++)
          zf[kt] = *reinterpret_cast<const bf16x8*>(smem + ZOFF + 1024 * kt + 16 * lane);
        f32x4 a0 = zero4, a1 = zero4;
#pragma unroll
        for (int kt = 0; kt < 4; kt++) {
          a0 = mfma16(wc[kt][0], zf[kt], a0);
          a1 = mfma16(wc[kt][1], zf[kt], a1);
        }
        a0 = mfma16(wc[4][0], uf, a0);
        a1 = mfma16(wc[4][1], uf, a1);
        if (crewB) {
          accl[0] = zero4; accl[1] = zero4;
#pragma unroll
          for (int kt = 0; kt < 4; kt++) {
            accl[0] = mfma16(wx[2 * kt + 0], zf[kt], accl[0]);
            accl[1] = mfma16(wx[2 * kt + 1], zf[kt], accl[1]);
          }
          accl[0] = mfma16(wx[8], uf, accl[0]);
          accl[1] = mfma16(wx[9], uf, accl[1]);
        }
#pragma unroll
        for (int i = 0; i < 2; i++) {
          f32x4 d = i ? a1 : a0;
          uint2 p;
          p.x = cvtpk(fmaxf(d[0] + bb1[i][0], 0.f), fmaxf(d[1] + bb1[i][1], 0.f));
          p.y = cvtpk(fmaxf(d[2] + bb1[i][2], 0.f), fmaxf(d[3] + bb1[i][3], 0.f));
          *reinterpret_cast<uint2*>(smem + H1OFF + 512 * (2 * v + i) + wby) = p;
        }
      }
      __syncthreads();
      // ---- S2: h2^T = W2 h1^T (crewA only, 4 tiles) ----
      if (!crewB) {
        f32x4 d[4] = {zero4, zero4, zero4, zero4};
#pragma unroll
        for (int half = 0; half < 2; half++) {
          bf16x8 g[4];
#pragma unroll
          for (int j = 0; j < 4; j++)
            g[j] = *reinterpret_cast<const bf16x8*>(
                smem + H1OFF + 1024 * (4 * half + j) + 16 * lane);
#pragma unroll
          for (int j = 0; j < 4; j++) {
            const int kt = 4 * half + j;
            d[0] = mfma16(wx[4 * kt + 0], g[j], d[0]);
            d[1] = mfma16(wx[4 * kt + 1], g[j], d[1]);
            d[2] = mfma16(wx[4 * kt + 2], g[j], d[2]);
            d[3] = mfma16(wx[4 * kt + 3], g[j], d[3]);
          }
        }
#pragma unroll
        for (int i = 0; i < 4; i++) {
          uint2 p;
          p.x = cvtpk(fmaxf(d[i][0] + bbx[i][0], 0.f), fmaxf(d[i][1] + bbx[i][1], 0.f));
          p.y = cvtpk(fmaxf(d[i][2] + bbx[i][2], 0.f), fmaxf(d[i][3] + bbx[i][3], 0.f));
          *reinterpret_cast<uint2*>(smem + H2OFF + 512 * (4 * v + i) + wby) = p;
        }
      }
      __syncthreads();
      // u[t+1]: issue raw loads early (e==0), convert late (e==3)
      if (e == 0 && t + 1 < TSTEPS) {
        const float* up = uin + ((size_t)(t + 1) * BATCH + wg * 16 + ln) * NUQ + 8 * q;
        ur0 = *reinterpret_cast<const f32x4*>(up);
        ur1 = *reinterpret_cast<const f32x4*>(up + 4);
      }
      if (e == 3 && t + 1 < TSTEPS) {
#pragma unroll
        for (int j = 0; j < 4; j++) {
          uf[j]     = (short)f2b(ur0[j]);
          uf[4 + j] = (short)f2b(ur1[j]);
        }
      }
      // ---- S3: k = W3 h2^T + lin + b3 ; RK4 update (crewB only) ----
      if (crewB) {
        f32x4 k0 = zero4, k1 = zero4;
#pragma unroll
        for (int half = 0; half < 2; half++) {
          bf16x8 g[4];
#pragma unroll
          for (int j = 0; j < 4; j++)
            g[j] = *reinterpret_cast<const bf16x8*>(
                smem + H2OFF + 1024 * (4 * half + j) + 16 * lane);
#pragma unroll
          for (int j = 0; j < 4; j++) {
            const int kt = 4 * half + j;
            k0 = mfma16(wx[10 + 2 * kt + 0], g[j], k0);
            k1 = mfma16(wx[10 + 2 * kt + 1], g[j], k1);
          }
        }
        const float wk = (e == 1 || e == 2) ? 2.0f : 1.0f;
        const float cn = (e == 2) ? dt : dth;
        f32x4 kk[2] = {k0, k1};
#pragma unroll
        for (int i = 0; i < 2; i++) {
          float xe[4];
#pragma unroll
          for (int r = 0; r < 4; r++) {
            float kv = kk[i][r] + accl[i][r] + bbx[i][r];
            if (e == 0) ksum[i][r] = kv; else ksum[i][r] += wk * kv;
            if (e == 3) { xs[i][r] += dt6 * ksum[i][r]; xe[r] = xs[i][r]; }
            else        { xe[r] = xs[i][r] + cn * kv; }
          }
          uint2 p;
          p.x = cvtpk(xe[0], xe[1]);
          p.y = cvtpk(xe[2], xe[3]);
          *reinterpret_cast<uint2*>(smem + ZOFF + 512 * (2 * w + i) + wby) = p;
          if (e == 3)
            *reinterpret_cast<uint2*>(
                xall + ((size_t)t * BATCH + wg * 16 + ln) * NXQ + 16 * (2 * w + i) + 4 * q) = p;
        }
      }
      __syncthreads();
    }
  }

  // x_final (f32), vectorized
  if (crewB) {
#pragma unroll
    for (int i = 0; i < 2; i++)
      *reinterpret_cast<f32x4*>(
          out + NY + (size_t)(wg * 16 + ln) * NXQ + 16 * (2 * w + i) + 4 * q) = xs[i];
  }
}

// ======================= Phase 2: bulk out_net GEMM =========================
// Processes y rows [16*slab .. ) for slabs in [slab0+blk*spw, slab_end).
__global__ __launch_bounds__(512, 2)
void outnet_kernel(const u16* __restrict__ xall,  // [rows][128] bf16
                   const float* __restrict__ Wo1, const float* __restrict__ bo1,
                   const float* __restrict__ Wo2, const float* __restrict__ bo2,
                   const float* __restrict__ Wo3, const float* __restrict__ bo3,
                   float* __restrict__ out,       // y [rows][128] f32
                   int slab0, int slab_end, int spw)
{
  __shared__ u16 h1[2][16][264];
  __shared__ u16 h2[2][16][264];

  const int tid  = threadIdx.x;
  const int lane = tid & 63;
  const int v    = tid >> 6;
  const int ln   = lane & 15;
  const int q    = lane >> 4;
  const int n1   = 16 * v + ln;
  const int n2   = 128 + n1;
  const f32x4 zero4 = {0.f, 0.f, 0.f, 0.f};

  bf16x8 f1[4][2];
#pragma unroll
  for (int kt = 0; kt < 4; kt++) {
    int k = 32 * kt + 8 * q;
    f1[kt][0] = ldw8f(Wo1 + n1 * NXQ + k);
    f1[kt][1] = ldw8f(Wo1 + n2 * NXQ + k);
  }
  bf16x8 f2[8][2];
#pragma unroll
  for (int kt = 0; kt < 8; kt++) {
    int k = 32 * kt + 8 * q;
    f2[kt][0] = ldw8f(Wo2 + n1 * NFQ + k);
    f2[kt][1] = ldw8f(Wo2 + n2 * NFQ + k);
  }
  bf16x8 f3[8];
#pragma unroll
  for (int kt = 0; kt < 8; kt++)
    f3[kt] = ldw8f(Wo3 + n1 * NFQ + 32 * kt + 8 * q);

  const float c1a = bo1[n1], c1b = bo1[n2];
  const float c2a = bo2[n1], c2b = bo2[n2];
  const float c3  = bo3[n1];

  const int s0  = slab0 + (int)blockIdx.x * spw;
  int cnt = slab_end - s0; if (cnt > spw) cnt = spw;
  if (cnt <= 0) return;

  bf16x8 a[4], an[4];
#pragma unroll
  for (int kt = 0; kt < 4; kt++)
    a[kt] = *reinterpret_cast<const bf16x8*>(
        &xall[((size_t)16 * s0 + ln) * NXQ + 32 * kt + 8 * q]);

#pragma unroll 1
  for (int i = 0; i < cnt; i++) {
    const int s = s0 + i, par = i & 1;
    if (i + 1 < cnt) {
#pragma unroll
      for (int kt = 0; kt < 4; kt++)
        an[kt] = *reinterpret_cast<const bf16x8*>(
            &xall[((size_t)16 * (s + 1) + ln) * NXQ + 32 * kt + 8 * q]);
    }
    // o1
    {
      f32x4 d0 = zero4, d1 = zero4;
#pragma unroll
      for (int kt = 0; kt < 4; kt++) {
        d0 = mfma16(a[kt], f1[kt][0], d0);
        d1 = mfma16(a[kt], f1[kt][1], d1);
      }
#pragma unroll
      for (int r = 0; r < 4; r++) {
        h1[par][4 * q + r][n1] = f2b(fmaxf(d0[r] + c1a, 0.f));
        h1[par][4 * q + r][n2] = f2b(fmaxf(d1[r] + c1b, 0.f));
      }
    }
    __syncthreads();
    // o2
    {
      bf16x8 c[8];
#pragma unroll
      for (int kt = 0; kt < 8; kt++)
        c[kt] = *reinterpret_cast<const bf16x8*>(&h1[par][ln][32 * kt + 8 * q]);
      f32x4 e0 = zero4, e1 = zero4;
#pragma unroll
      for (int kt = 0; kt < 8; kt++) {
        e0 = mfma16(c[kt], f2[kt][0], e0);
        e1 = mfma16(c[kt], f2[kt][1], e1);
      }
#pragma unroll
      for (int r = 0; r < 4; r++) {
        h2[par][4 * q + r][n1] = f2b(fmaxf(e0[r] + c2a, 0.f));
        h2[par][4 * q + r][n2] = f2b(fmaxf(e1[r] + c2b, 0.f));
      }
    }
    __syncthreads();
    // o3 -> y (f32); no trailing barrier (ping-pong buffers)
    {
      bf16x8 g[8];
#pragma unroll
      for (int kt = 0; kt < 8; kt++)
        g[kt] = *reinterpret_cast<const bf16x8*>(&h2[par][ln][32 * kt + 8 * q]);
      f32x4 y = zero4;
#pragma unroll
      for (int kt = 0; kt < 8; kt++) y = mfma16(g[kt], f3[kt], y);
#pragma unroll
      for (int r = 0; r < 4; r++)
        out[((size_t)16 * s + 4 * q + r) * NXQ + n1] = y[r] + c3;
    }
#pragma unroll
    for (int kt = 0; kt < 4; kt++) a[kt] = an[kt];
  }
}

extern "C" void kernel_launch(void* const* d_in, const int* in_sizes, int n_in,
                              void* d_out, int out_size, void* d_ws, size_t ws_size,
                              hipStream_t stream) {
  const float* uin  = (const float*)d_in[0];
  const float* x0   = (const float*)d_in[1];
  const float* dtp  = (const float*)d_in[2];
  const float* Wlin = (const float*)d_in[3];
  const float* W1   = (const float*)d_in[4];
  const float* b1   = (const float*)d_in[5];
  const float* W2   = (const float*)d_in[6];
  const float* b2   = (const float*)d_in[7];
  const float* W3   = (const float*)d_in[8];
  const float* b3   = (const float*)d_in[9];
  const float* Wo1  = (const float*)d_in[10];
  const float* bo1  = (const float*)d_in[11];
  const float* Wo2  = (const float*)d_in[12];
  const float* bo2  = (const float*)d_in[13];
  const float* Wo3  = (const float*)d_in[14];
  const float* bo3  = (const float*)d_in[15];
  float* out = (float*)d_out;

  const size_t xall_bytes = NY * sizeof(u16);   // 64 MiB
  const bool ws_ok = (ws_size >= xall_bytes);
  u16* xall = ws_ok ? (u16*)d_ws : (u16*)d_out;  // fallback: front of y region

  scan_kernel<<<dim3(64), dim3(512), 0, stream>>>(
      uin, x0, dtp, Wlin, W1, b1, W2, b2, W3, b3, xall, out);

  const int nslab = TSTEPS * BATCH / 16;        // 16384
  if (ws_ok) {
    const int spw = 32;
    outnet_kernel<<<dim3(nslab / spw), dim3(512), 0, stream>>>(
        xall, Wo1, bo1, Wo2, bo2, Wo3, bo3, out, 0, nslab, spw);
  } else {
    // y[slab s] overwrites x-slabs [2s,2s+2): process [S,2S) in halving
    // passes so clobbered x-slabs are always already consumed.
    for (int S = nslab / 2; S >= 1; S >>= 1) {
      int grid = S < 512 ? S : 512;
      int spw  = (S + grid - 1) / grid;
      outnet_kernel<<<dim3(grid), dim3(512), 0, stream>>>(
          xall, Wo1, bo1, Wo2, bo2, Wo3, bo3, out, S, 2 * S, spw);
    }
    outnet_kernel<<<dim3(1), dim3(512), 0, stream>>>(
        xall, Wo1, bo1, Wo2, bo2, Wo3, bo3, out, 0, 1, 1);
  }
}

// Round 3
// 1456.935 us; speedup vs baseline: 1.7294x; 1.4393x over previous
//
#include <hip/hip_runtime.h>

// ODELayer RK4 scan — R7 "balanced uniform swapped-operand":
//   Lesson R5/R6: crew-specialized stages idle half the waves per interval
//   (1 wave/SIMD active -> latency exposed) and the 42-frag weight file
//   spilled. R4's balanced all-wave layout overlapped better despite more
//   LDS traffic.
//   R7: every wave works every stage, with the swapped-operand B-frag
//   dataflow (weights = register A-frags, activations = LDS B-frags,
//   epilogue = cvt_pk + one ds_write_b64 per tile):
//     S1: wave v -> h1-tiles {2v,2v+1} (10 MFMA) + lin-tile v (5 MFMA,
//         accl stays in registers until S3).
//     S2: wave v -> h2-tiles {2v,2v+1} (16 MFMA).
//     S3: wave v -> k-tile v (8 MFMA, two depth-4 chains) + RK4 state for
//         feats [16v,16v+16) x batch ln.
//   39 weight frags/wave (156 VGPR) + biases in registers.
// Phase 2 (outnet_kernel) unchanged.

#define TSTEPS 256
#define BATCH  1024
#define NUQ    32
#define NXQ    128
#define NFQ    256
#define NINQ   160
#define NY     ((size_t)TSTEPS * BATCH * NXQ)

typedef __attribute__((ext_vector_type(8))) short bf16x8;
typedef __attribute__((ext_vector_type(4))) short s16x4;
typedef __attribute__((ext_vector_type(4))) float f32x4;
typedef unsigned short u16;

__device__ __forceinline__ u16 f2b(float f) {
  unsigned u = __float_as_uint(f);
  u = (u + 0x7FFFu + ((u >> 16) & 1u)) >> 16;
  return (u16)u;
}
__device__ __forceinline__ unsigned cvtpk(float a, float b) {
  unsigned r;
  asm("v_cvt_pk_bf16_f32 %0, %1, %2" : "=v"(r) : "v"(a), "v"(b));
  return r;
}
__device__ __forceinline__ f32x4 mfma16(bf16x8 a, bf16x8 b, f32x4 c) {
  return __builtin_amdgcn_mfma_f32_16x16x32_bf16(a, b, c, 0, 0, 0);
}
// 8 consecutive f32 weights -> bf16 fragment (16B-aligned source).
__device__ __forceinline__ bf16x8 ldw8f(const float* p) {
  f32x4 a = *reinterpret_cast<const f32x4*>(p);
  f32x4 b = *reinterpret_cast<const f32x4*>(p + 4);
  bf16x8 r;
  r[0] = (short)f2b(a[0]); r[1] = (short)f2b(a[1]);
  r[2] = (short)f2b(a[2]); r[3] = (short)f2b(a[3]);
  r[4] = (short)f2b(b[0]); r[5] = (short)f2b(b[1]);
  r[6] = (short)f2b(b[2]); r[7] = (short)f2b(b[3]);
  return r;
}

// LDS map: B-frag buffers, frag = [64 lanes][16B], frag kt at +1024*kt.
// Output tile T (16 feat x 16 batch, 512B) lives at frag T>>1, half T&1.
#define ZOFF  0       // z^T x-part: 4 frags (4 KiB)
#define H1OFF 4096    // h1^T: 8 frags (8 KiB)
#define H2OFF 12288   // h2^T: 8 frags (8 KiB)
#define SMEMB 20480

// ======================= Phase 1: the sequential scan =======================
__global__ __launch_bounds__(512, 2)
void scan_kernel(const float* __restrict__ uin,   // [256][1024][32]
                 const float* __restrict__ x0,    // [1024][128]
                 const float* __restrict__ dtp,
                 const float* __restrict__ Wlin,  // [128][160]
                 const float* __restrict__ W1,    // [256][160]
                 const float* __restrict__ b1,    // [256]
                 const float* __restrict__ W2,    // [256][256]
                 const float* __restrict__ b2,    // [256]
                 const float* __restrict__ W3,    // [128][256]
                 const float* __restrict__ b3,    // [128]
                 u16* __restrict__ xall,          // [256][1024][128] bf16
                 float* __restrict__ out)         // xf at out[NY..]
{
  __shared__ __align__(16) char smem[SMEMB];

  const int tid  = threadIdx.x;
  const int wg   = blockIdx.x;            // batch rows wg*16..+15
  const int lane = tid & 63;
  const int v    = tid >> 6;              // wave 0..7
  const int ln   = lane & 15;             // batch index within row-group
  const int q    = lane >> 4;

  const float dt  = dtp[0];
  const float dth = 0.5f * dt;
  const float dt6 = dt * (1.0f / 6.0f);
  const f32x4 zero4 = {0.f, 0.f, 0.f, 0.f};

  // Producer-side write offset within a frag pair:
  // value (feat 16T+4q+r, batch ln) -> byte 512*T + wby (+2r inside the b64)
  const int wby = 256 * (q >> 1) + 16 * ln + 8 * (q & 1);

  // ---------------- register-resident A-fragments (weights) ----------------
  // A-frag for n-tile T, K-tile kt: lane holds W[16T+ln][32kt+8q+j], j=0..7.
  bf16x8 wc[5][2];   // W1, h1-tiles {2v, 2v+1}
  bf16x8 wl[5];      // Wlin, lin-tile v
  bf16x8 w2[8][2];   // W2, h2-tiles {2v, 2v+1}
  bf16x8 w3[8];      // W3, k-tile v
#pragma unroll
  for (int kt = 0; kt < 5; kt++) {
#pragma unroll
    for (int i = 0; i < 2; i++)
      wc[kt][i] = ldw8f(W1 + (size_t)(16 * (2 * v + i) + ln) * NINQ + 32 * kt + 8 * q);
    wl[kt] = ldw8f(Wlin + (size_t)(16 * v + ln) * NINQ + 32 * kt + 8 * q);
  }
#pragma unroll
  for (int kt = 0; kt < 8; kt++) {
#pragma unroll
    for (int i = 0; i < 2; i++)
      w2[kt][i] = ldw8f(W2 + (size_t)(16 * (2 * v + i) + ln) * NFQ + 32 * kt + 8 * q);
    w3[kt] = ldw8f(W3 + (size_t)(16 * v + ln) * NFQ + 32 * kt + 8 * q);
  }

  // ---- biases in registers (barriers block LICM of in-loop reloads) ----
  f32x4 bb1[2], bb2[2], bb3;
#pragma unroll
  for (int i = 0; i < 2; i++) {
    bb1[i] = *reinterpret_cast<const f32x4*>(b1 + 16 * (2 * v + i) + 4 * q);
    bb2[i] = *reinterpret_cast<const f32x4*>(b2 + 16 * (2 * v + i) + 4 * q);
  }
  bb3 = *reinterpret_cast<const f32x4*>(b3 + 16 * v + 4 * q);

  // RK4 state: xs[r] = x[batch ln][xdim 16v+4q+r]
  f32x4 xs, ksum, accl;
  xs = *reinterpret_cast<const f32x4*>(
      x0 + (size_t)(wg * 16 + ln) * NXQ + 16 * v + 4 * q);
  {
    uint2 p;
    p.x = cvtpk(xs[0], xs[1]);
    p.y = cvtpk(xs[2], xs[3]);
    *reinterpret_cast<uint2*>(smem + ZOFF + 512 * v + wby) = p;
  }
  // u B-frag (register-resident): lane holds u[ln][8q+j]
  bf16x8 uf = ldw8f(uin + (size_t)(wg * 16 + ln) * NUQ + 8 * q);
  f32x4 ur0 = zero4, ur1 = zero4;        // raw u[t+1], issued at e==0
  __syncthreads();

#pragma unroll 1
  for (int t = 0; t < TSTEPS; t++) {
#pragma unroll 1
    for (int e = 0; e < 4; e++) {
      // ---- S1: h1^T = W1 z^T (2 tiles) + lin-tile v (kept in regs) ----
      {
        bf16x8 zf[4];
#pragma unroll
        for (int kt = 0; kt < 4; kt++)
          zf[kt] = *reinterpret_cast<const bf16x8*>(smem + ZOFF + 1024 * kt + 16 * lane);
        f32x4 a0 = zero4, a1 = zero4, al = zero4;
#pragma unroll
        for (int kt = 0; kt < 4; kt++) {
          a0 = mfma16(wc[kt][0], zf[kt], a0);
          a1 = mfma16(wc[kt][1], zf[kt], a1);
          al = mfma16(wl[kt], zf[kt], al);
        }
        a0 = mfma16(wc[4][0], uf, a0);
        a1 = mfma16(wc[4][1], uf, a1);
        al = mfma16(wl[4], uf, al);
        accl = al;
#pragma unroll
        for (int i = 0; i < 2; i++) {
          f32x4 d = i ? a1 : a0;
          uint2 p;
          p.x = cvtpk(fmaxf(d[0] + bb1[i][0], 0.f), fmaxf(d[1] + bb1[i][1], 0.f));
          p.y = cvtpk(fmaxf(d[2] + bb1[i][2], 0.f), fmaxf(d[3] + bb1[i][3], 0.f));
          *reinterpret_cast<uint2*>(smem + H1OFF + 512 * (2 * v + i) + wby) = p;
        }
      }
      __syncthreads();
      // ---- S2: h2^T = W2 h1^T (2 tiles) ----
      {
        bf16x8 g[8];
#pragma unroll
        for (int kt = 0; kt < 8; kt++)
          g[kt] = *reinterpret_cast<const bf16x8*>(smem + H1OFF + 1024 * kt + 16 * lane);
        f32x4 d0 = zero4, d1 = zero4;
#pragma unroll
        for (int kt = 0; kt < 8; kt++) {
          d0 = mfma16(w2[kt][0], g[kt], d0);
          d1 = mfma16(w2[kt][1], g[kt], d1);
        }
#pragma unroll
        for (int i = 0; i < 2; i++) {
          f32x4 d = i ? d1 : d0;
          uint2 p;
          p.x = cvtpk(fmaxf(d[0] + bb2[i][0], 0.f), fmaxf(d[1] + bb2[i][1], 0.f));
          p.y = cvtpk(fmaxf(d[2] + bb2[i][2], 0.f), fmaxf(d[3] + bb2[i][3], 0.f));
          *reinterpret_cast<uint2*>(smem + H2OFF + 512 * (2 * v + i) + wby) = p;
        }
      }
      __syncthreads();
      // u[t+1]: issue raw loads early (e==0), convert late (e==3)
      if (e == 0 && t + 1 < TSTEPS) {
        const float* up = uin + ((size_t)(t + 1) * BATCH + wg * 16 + ln) * NUQ + 8 * q;
        ur0 = *reinterpret_cast<const f32x4*>(up);
        ur1 = *reinterpret_cast<const f32x4*>(up + 4);
      }
      if (e == 3 && t + 1 < TSTEPS) {
#pragma unroll
        for (int j = 0; j < 4; j++) {
          uf[j]     = (short)f2b(ur0[j]);
          uf[4 + j] = (short)f2b(ur1[j]);
        }
      }
      // ---- S3: k-tile v = W3 h2^T + lin + b3 ; RK4 update ----
      {
        bf16x8 g[8];
#pragma unroll
        for (int kt = 0; kt < 8; kt++)
          g[kt] = *reinterpret_cast<const bf16x8*>(smem + H2OFF + 1024 * kt + 16 * lane);
        f32x4 ka = zero4, kb = zero4;     // two depth-4 chains
#pragma unroll
        for (int j = 0; j < 4; j++) {
          ka = mfma16(w3[j], g[j], ka);
          kb = mfma16(w3[4 + j], g[4 + j], kb);
        }
        const float wk = (e == 1 || e == 2) ? 2.0f : 1.0f;
        const float cn = (e == 2) ? dt : dth;
        float xe[4];
#pragma unroll
        for (int r = 0; r < 4; r++) {
          float kv = ka[r] + kb[r] + accl[r] + bb3[r];
          if (e == 0) ksum[r] = kv; else ksum[r] += wk * kv;
          if (e == 3) { xs[r] += dt6 * ksum[r]; xe[r] = xs[r]; }
          else        { xe[r] = xs[r] + cn * kv; }
        }
        uint2 p;
        p.x = cvtpk(xe[0], xe[1]);
        p.y = cvtpk(xe[2], xe[3]);
        *reinterpret_cast<uint2*>(smem + ZOFF + 512 * v + wby) = p;
        if (e == 3)
          *reinterpret_cast<uint2*>(
              xall + ((size_t)t * BATCH + wg * 16 + ln) * NXQ + 16 * v + 4 * q) = p;
      }
      __syncthreads();
    }
  }

  // x_final (f32), vectorized
  *reinterpret_cast<f32x4*>(
      out + NY + (size_t)(wg * 16 + ln) * NXQ + 16 * v + 4 * q) = xs;
}

// ======================= Phase 2: bulk out_net GEMM =========================
// Processes y rows [16*slab .. ) for slabs in [slab0+blk*spw, slab_end).
__global__ __launch_bounds__(512, 2)
void outnet_kernel(const u16* __restrict__ xall,  // [rows][128] bf16
                   const float* __restrict__ Wo1, const float* __restrict__ bo1,
                   const float* __restrict__ Wo2, const float* __restrict__ bo2,
                   const float* __restrict__ Wo3, const float* __restrict__ bo3,
                   float* __restrict__ out,       // y [rows][128] f32
                   int slab0, int slab_end, int spw)
{
  __shared__ u16 h1[2][16][264];
  __shared__ u16 h2[2][16][264];

  const int tid  = threadIdx.x;
  const int lane = tid & 63;
  const int v    = tid >> 6;
  const int ln   = lane & 15;
  const int q    = lane >> 4;
  const int n1   = 16 * v + ln;
  const int n2   = 128 + n1;
  const f32x4 zero4 = {0.f, 0.f, 0.f, 0.f};

  bf16x8 f1[4][2];
#pragma unroll
  for (int kt = 0; kt < 4; kt++) {
    int k = 32 * kt + 8 * q;
    f1[kt][0] = ldw8f(Wo1 + n1 * NXQ + k);
    f1[kt][1] = ldw8f(Wo1 + n2 * NXQ + k);
  }
  bf16x8 f2[8][2];
#pragma unroll
  for (int kt = 0; kt < 8; kt++) {
    int k = 32 * kt + 8 * q;
    f2[kt][0] = ldw8f(Wo2 + n1 * NFQ + k);
    f2[kt][1] = ldw8f(Wo2 + n2 * NFQ + k);
  }
  bf16x8 f3[8];
#pragma unroll
  for (int kt = 0; kt < 8; kt++)
    f3[kt] = ldw8f(Wo3 + n1 * NFQ + 32 * kt + 8 * q);

  const float c1a = bo1[n1], c1b = bo1[n2];
  const float c2a = bo2[n1], c2b = bo2[n2];
  const float c3  = bo3[n1];

  const int s0  = slab0 + (int)blockIdx.x * spw;
  int cnt = slab_end - s0; if (cnt > spw) cnt = spw;
  if (cnt <= 0) return;

  bf16x8 a[4], an[4];
#pragma unroll
  for (int kt = 0; kt < 4; kt++)
    a[kt] = *reinterpret_cast<const bf16x8*>(
        &xall[((size_t)16 * s0 + ln) * NXQ + 32 * kt + 8 * q]);

#pragma unroll 1
  for (int i = 0; i < cnt; i++) {
    const int s = s0 + i, par = i & 1;
    if (i + 1 < cnt) {
#pragma unroll
      for (int kt = 0; kt < 4; kt++)
        an[kt] = *reinterpret_cast<const bf16x8*>(
            &xall[((size_t)16 * (s + 1) + ln) * NXQ + 32 * kt + 8 * q]);
    }
    // o1
    {
      f32x4 d0 = zero4, d1 = zero4;
#pragma unroll
      for (int kt = 0; kt < 4; kt++) {
        d0 = mfma16(a[kt], f1[kt][0], d0);
        d1 = mfma16(a[kt], f1[kt][1], d1);
      }
#pragma unroll
      for (int r = 0; r < 4; r++) {
        h1[par][4 * q + r][n1] = f2b(fmaxf(d0[r] + c1a, 0.f));
        h1[par][4 * q + r][n2] = f2b(fmaxf(d1[r] + c1b, 0.f));
      }
    }
    __syncthreads();
    // o2
    {
      bf16x8 c[8];
#pragma unroll
      for (int kt = 0; kt < 8; kt++)
        c[kt] = *reinterpret_cast<const bf16x8*>(&h1[par][ln][32 * kt + 8 * q]);
      f32x4 e0 = zero4, e1 = zero4;
#pragma unroll
      for (int kt = 0; kt < 8; kt++) {
        e0 = mfma16(c[kt], f2[kt][0], e0);
        e1 = mfma16(c[kt], f2[kt][1], e1);
      }
#pragma unroll
      for (int r = 0; r < 4; r++) {
        h2[par][4 * q + r][n1] = f2b(fmaxf(e0[r] + c2a, 0.f));
        h2[par][4 * q + r][n2] = f2b(fmaxf(e1[r] + c2b, 0.f));
      }
    }
    __syncthreads();
    // o3 -> y (f32); no trailing barrier (ping-pong buffers)
    {
      bf16x8 g[8];
#pragma unroll
      for (int kt = 0; kt < 8; kt++)
        g[kt] = *reinterpret_cast<const bf16x8*>(&h2[par][ln][32 * kt + 8 * q]);
      f32x4 y = zero4;
#pragma unroll
      for (int kt = 0; kt < 8; kt++) y = mfma16(g[kt], f3[kt], y);
#pragma unroll
      for (int r = 0; r < 4; r++)
        out[((size_t)16 * s + 4 * q + r) * NXQ + n1] = y[r] + c3;
    }
#pragma unroll
    for (int kt = 0; kt < 4; kt++) a[kt] = an[kt];
  }
}

extern "C" void kernel_launch(void* const* d_in, const int* in_sizes, int n_in,
                              void* d_out, int out_size, void* d_ws, size_t ws_size,
                              hipStream_t stream) {
  const float* uin  = (const float*)d_in[0];
  const float* x0   = (const float*)d_in[1];
  const float* dtp  = (const float*)d_in[2];
  const float* Wlin = (const float*)d_in[3];
  const float* W1   = (const float*)d_in[4];
  const float* b1   = (const float*)d_in[5];
  const float* W2   = (const float*)d_in[6];
  const float* b2   = (const float*)d_in[7];
  const float* W3   = (const float*)d_in[8];
  const float* b3   = (const float*)d_in[9];
  const float* Wo1  = (const float*)d_in[10];
  const float* bo1  = (const float*)d_in[11];
  const float* Wo2  = (const float*)d_in[12];
  const float* bo2  = (const float*)d_in[13];
  const float* Wo3  = (const float*)d_in[14];
  const float* bo3  = (const float*)d_in[15];
  float* out = (float*)d_out;

  const size_t xall_bytes = NY * sizeof(u16);   // 64 MiB
  const bool ws_ok = (ws_size >= xall_bytes);
  u16* xall = ws_ok ? (u16*)d_ws : (u16*)d_out;  // fallback: front of y region

  scan_kernel<<<dim3(64), dim3(512), 0, stream>>>(
      uin, x0, dtp, Wlin, W1, b1, W2, b2, W3, b3, xall, out);

  const int nslab = TSTEPS * BATCH / 16;        // 16384
  if (ws_ok) {
    const int spw = 32;
    outnet_kernel<<<dim3(nslab / spw), dim3(512), 0, stream>>>(
        xall, Wo1, bo1, Wo2, bo2, Wo3, bo3, out, 0, nslab, spw);
  } else {
    // y[slab s] overwrites x-slabs [2s,2s+2): process [S,2S) in halving
    // passes so clobbered x-slabs are always already consumed.
    for (int S = nslab / 2; S >= 1; S >>= 1) {
      int grid = S < 512 ? S : 512;
      int spw  = (S + grid - 1) / grid;
      outnet_kernel<<<dim3(grid), dim3(512), 0, stream>>>(
          xall, Wo1, bo1, Wo2, bo2, Wo3, bo3, out, S, 2 * S, spw);
    }
    outnet_kernel<<<dim3(1), dim3(512), 0, stream>>>(
        xall, Wo1, bo1, Wo2, bo2, Wo3, bo3, out, 0, 1, 1);
  }
}